// Round 5
// baseline (221.473 us; speedup 1.0000x reference)
//
#include <hip/hip_runtime.h>
#include <math.h>

#define D       256
#define KCODES  1024
#define NROWS   65536
#define BETA    0.25f
#define MARGIN  1e-3f
#define MAXSURV 7

typedef __attribute__((ext_vector_type(8))) short bf16x8;
typedef __attribute__((ext_vector_type(4))) float f32x4;

__device__ __forceinline__ unsigned int bf16_rne(float f) {
    unsigned int u = __float_as_uint(f);
    return (u + 0x7FFFu + ((u >> 16) & 1u)) >> 16;   // RNE bf16 (inputs are finite/normal)
}
__device__ __forceinline__ f32x4 mfma16(bf16x8 a, bf16x8 b, f32x4 c) {
    return __builtin_amdgcn_mfma_f32_16x16x32_bf16(a, b, c, 0, 0, 0);
}

// ---------- codebook -> bf16 (hi only, RNE): cs[k][0:256]; e2f exact ----------
__global__ __launch_bounds__(256) void split_cb_kernel(const float* __restrict__ cb,
                                                       ushort* __restrict__ cs,
                                                       float* __restrict__ e2f) {
    int code = blockIdx.x * 4 + (threadIdx.x >> 6);
    int lane = threadIdx.x & 63;
    float4 v = ((const float4*)(cb + (size_t)code * D))[lane];
    double s = (double)v.x * v.x + (double)v.y * v.y +
               (double)v.z * v.z + (double)v.w * v.w;
    ushort* ph = cs + (size_t)code * 256 + lane * 4;
    ph[0] = (ushort)bf16_rne(v.x); ph[1] = (ushort)bf16_rne(v.y);
    ph[2] = (ushort)bf16_rne(v.z); ph[3] = (ushort)bf16_rne(v.w);
    #pragma unroll
    for (int off = 32; off > 0; off >>= 1) s += __shfl_down(s, off, 64);
    if (lane == 0) e2f[code] = (float)s;
}

// ---------- MFMA screening v6: 64 rows/wave (4 M-tiles) -> B-tile LDS reads and staging
// writes per CU HALVE vs v4 (the dominant pipe). 256-thread blocks (4 waves, 256 rows),
// grid = 256 = 1 block/CU. (distance,index) packed into one uint:
// u = (as_uint(dist + 0.5) & ~1023) | k  -- positive by Cauchy-Schwarz (|2*sim| <= 0.38),
// quantization <= 6e-5 absorbed by MARGIN. Merge in two 128-row phases aliased into Bt[0].
__global__ __launch_bounds__(256, 1) void screen_kernel(
    const float* __restrict__ x, const ushort* __restrict__ cs,
    const float* __restrict__ e2f, float* __restrict__ x2f,
    ushort* __restrict__ rowlist)
{
    __shared__ __attribute__((aligned(16))) ushort Bt[2][32 * 264];  // 2 x 16,896 B
    // merge scratch aliased into Bt[0] (128 rows x 33 u32 = 16,896 B = sizeof(Bt[0])).
    // Safe: Bt[0]'s last reader is compute(kt=30), which precedes the kt=31 barrier that
    // every wave passed before exiting the K-loop; concurrent compute(31) reads Bt[1].
    unsigned* mrg = (unsigned*)&Bt[0][0];
    #define MRG(r, j) mrg[(r) * 33 + (j)]

    const int tid  = threadIdx.x;
    const int wave = tid >> 6, lane = tid & 63;
    const int quad = lane >> 4, m = lane & 15;
    const int rowBase = blockIdx.x * 256;
    const int wrb = rowBase + wave * 64;       // this wave's 64 rows (4 M-tiles)

    // ---- issue tile-0 staging loads first: latency hides under the A-fragment build ----
    const int sc = tid & 31, sp = tid >> 5;    // staging: code 0..31, part 0..7 (32 ushorts)
    bf16x8 stg[4];
    {
        const ushort* src = cs + (size_t)sc * 256 + sp * 32;
        #pragma unroll
        for (int i = 0; i < 4; ++i) stg[i] = *(const bf16x8*)&src[i * 8];
    }

    // ---- build A fragments (bf16 hi) in registers from fp32 x; accumulate exact x2 ----
    bf16x8 af[4][8];                           // 128 VGPRs
    #pragma unroll
    for (int t = 0; t < 4; ++t) {
        const float* xr = x + (size_t)(wrb + t * 16 + m) * D;
        double s = 0.0;
        #pragma unroll
        for (int c = 0; c < 8; ++c) {
            float4 f0 = *(const float4*)&xr[c * 32 + quad * 8];
            float4 f1 = *(const float4*)&xr[c * 32 + quad * 8 + 4];
            s += (double)f0.x * f0.x + (double)f0.y * f0.y +
                 (double)f0.z * f0.z + (double)f0.w * f0.w;
            s += (double)f1.x * f1.x + (double)f1.y * f1.y +
                 (double)f1.z * f1.z + (double)f1.w * f1.w;
            float ff[8] = {f0.x, f0.y, f0.z, f0.w, f1.x, f1.y, f1.z, f1.w};
            #pragma unroll
            for (int j = 0; j < 8; ++j) af[t][c][j] = (short)bf16_rne(ff[j]);
        }
        s += __shfl_xor(s, 16, 64);
        s += __shfl_xor(s, 32, 64);
        if (quad == 0) x2f[wrb + t * 16 + m] = (float)s;
    }

    // ---- packed top-2 per (Mtile,row-reg) over this lane's code class ----
    unsigned u1[4][4], u2[4][4];
    #pragma unroll
    for (int t = 0; t < 4; ++t)
        #pragma unroll
        for (int r = 0; r < 4; ++r) { u1[t][r] = 0xFFFFFFFFu; u2[t][r] = 0xFFFFFFFFu; }

    // Pipeline per kt:  [ds_write stg(kt) -> buf[kt&1]]  barrier
    //                   [issue global loads stg := tile kt+1]  [compute(kt) from buf[kt&1]]
    for (int kt = 0; kt < KCODES / 32; ++kt) {
        {
            ushort* dst = &Bt[kt & 1][sc * 264 + sp * 32];
            #pragma unroll
            for (int i = 0; i < 4; ++i) *(bf16x8*)&dst[i * 8] = stg[i];
        }
        __syncthreads();                        // buf[kt&1] visible to all waves
        if (kt < KCODES / 32 - 1) {
            const ushort* src = cs + (size_t)((kt + 1) * 32 + sc) * 256 + sp * 32;
            #pragma unroll
            for (int i = 0; i < 4; ++i) stg[i] = *(const bf16x8*)&src[i * 8];
        }

        // e2 prefetch (+0.5 pack bias folded in) before the MFMA clusters
        float e2pa = e2f[kt * 32 + m] + 0.5f;
        float e2pb = e2f[kt * 32 + 16 + m] + 0.5f;

        const ushort* Bcur = &Bt[kt & 1][0];
        #pragma unroll
        for (int nt = 0; nt < 2; ++nt) {
            f32x4 acc0 = {0.f, 0.f, 0.f, 0.f};
            f32x4 acc1 = {0.f, 0.f, 0.f, 0.f};
            f32x4 acc2 = {0.f, 0.f, 0.f, 0.f};
            f32x4 acc3 = {0.f, 0.f, 0.f, 0.f};
            const ushort* bp = Bcur + (nt * 16 + m) * 264 + quad * 8;
            __builtin_amdgcn_s_setprio(1);
            #pragma unroll
            for (int c = 0; c < 8; ++c) {
                bf16x8 bh = *(const bf16x8*)&bp[c * 32];
                acc0 = mfma16(af[0][c], bh, acc0);
                acc1 = mfma16(af[1][c], bh, acc1);
                acc2 = mfma16(af[2][c], bh, acc2);
                acc3 = mfma16(af[3][c], bh, acc3);
            }
            __builtin_amdgcn_s_setprio(0);
            unsigned kcode = kt * 32 + nt * 16 + m;
            float e2p = nt ? e2pb : e2pa;
            #pragma unroll
            for (int t = 0; t < 4; ++t) {
                f32x4 acc = (t == 0) ? acc0 : (t == 1) ? acc1 : (t == 2) ? acc2 : acc3;
                #pragma unroll
                for (int r = 0; r < 4; ++r) {
                    float d = fmaf(-2.f, acc[r], e2p);          // dist + 0.5 (> 0)
                    unsigned u = (__float_as_uint(d) & 0xFFFFFC00u) | kcode;
                    bool lt1 = u < u1[t][r];
                    bool lt2 = u < u2[t][r];
                    u2[t][r] = lt2 ? (lt1 ? u1[t][r] : u) : u2[t][r];
                    u1[t][r] = lt1 ? u : u1[t][r];
                }
            }
        }
    }

    // ---- per-row merge, two 128-row phases (mrg aliases Bt[0]; see safety note) ----
    #pragma unroll
    for (int ph = 0; ph < 2; ++ph) {
        if ((wave >> 1) == ph) {               // waves 0,1 in phase 0; waves 2,3 in phase 1
            #pragma unroll
            for (int t = 0; t < 4; ++t)
                #pragma unroll
                for (int r = 0; r < 4; ++r) {
                    int rowloc = (wave & 1) * 64 + t * 16 + quad * 4 + r;
                    MRG(rowloc, m * 2 + 0) = u1[t][r];
                    MRG(rowloc, m * 2 + 1) = u2[t][r];
                }
        }
        __syncthreads();
        if (tid < 128) {
            unsigned umin = 0xFFFFFFFFu;
            #pragma unroll
            for (int j = 0; j < 32; ++j) umin = min(umin, MRG(tid, j));
            float dfloor = __uint_as_float(umin & 0xFFFFFC00u);
            unsigned limu = (__float_as_uint(dfloor + MARGIN) & 0xFFFFFC00u) | 1023u;
            ushort out[8] = {0, 0, 0, 0, 0, 0, 0, 0};
            int cnt = 0;
            for (int j = 0; j < 32; ++j) {
                unsigned u = MRG(tid, j);
                if (u <= limu && cnt < MAXSURV) { out[1 + cnt] = (ushort)(u & 1023u); ++cnt; }
            }
            out[0] = (ushort)cnt;
            *(bf16x8*)&rowlist[(size_t)(rowBase + ph * 128 + tid) * 8] = *(bf16x8*)out;
        }
        __syncthreads();
    }
    #undef MRG
}

// ---------- exact rescore + gather + mse partial: one wave per row ----------
__global__ __launch_bounds__(256) void rescore_kernel(
    const float* __restrict__ x, const float* __restrict__ cb,
    const float* __restrict__ x2f, const float* __restrict__ e2f,
    const ushort* __restrict__ rowlist, float* __restrict__ out_idxf,
    unsigned int* __restrict__ counts, float* __restrict__ y,
    float* __restrict__ msepart)
{
    int row  = blockIdx.x * 4 + (threadIdx.x >> 6);
    int lane = threadIdx.x & 63;
    const ushort* lst = rowlist + (size_t)row * 8;
    int cnt = lst[0];
    float4 xv = ((const float4*)(x + (size_t)row * D))[lane];

    int bk;
    if (cnt == 1) {
        bk = lst[1];                            // fast path: single survivor
    } else {
        float x2 = x2f[row];
        float bestd = 1e30f;
        int   bestk = 0;
        for (int s = 0; s < cnt; ++s) {
            int k = lst[1 + s];
            float4 cv = ((const float4*)(cb + (size_t)k * D))[lane];
            double p = (double)xv.x * cv.x + (double)xv.y * cv.y +
                       (double)xv.z * cv.z + (double)xv.w * cv.w;
            #pragma unroll
            for (int off = 32; off > 0; off >>= 1) p += __shfl_down(p, off, 64);
            float simf = (float)p;              // correctly-rounded f32 sim (lane 0 exact)
            float tt   = x2 + e2f[k];           // fl32(x2+e2)
            float dq   = tt - 2.0f * simf;      // reference comparator
            if (dq < bestd || (dq == bestd && k < bestk)) { bestd = dq; bestk = k; }
        }
        bk = __shfl(bestk, 0, 64);              // lane 0 had the exact sums
    }
    if (lane == 0) {
        out_idxf[row] = (float)bk;
        atomicAdd(&counts[bk], 1u);             // 1024 distinct addresses -> low contention
    }
    // gather + y + mse partial
    float4 q = ((const float4*)(cb + (size_t)bk * D))[lane];
    float4 dv;
    dv.x = q.x - xv.x; dv.y = q.y - xv.y; dv.z = q.z - xv.z; dv.w = q.w - xv.w;
    float4 yv;
    yv.x = xv.x + dv.x; yv.y = xv.y + dv.y; yv.z = xv.z + dv.z; yv.w = xv.w + dv.w;
    ((float4*)(y + (size_t)row * D))[lane] = yv;
    float s = dv.x * dv.x + dv.y * dv.y + dv.z * dv.z + dv.w * dv.w;
    #pragma unroll
    for (int off = 32; off > 0; off >>= 1) s += __shfl_down(s, off, 64);
    if (lane == 0) msepart[row] = s;            // plain store, no atomic
}

// ---------- final scalars: reduce msepart + counts -> loss, perplexity, usage, H ----------
__global__ __launch_bounds__(1024) void stats_kernel(
    const unsigned int* __restrict__ counts, const float* __restrict__ msepart,
    float* __restrict__ outs)
{
    int t = threadIdx.x;
    // mse partial reduction: 64 coalesced strided reads per thread
    float ms = 0.f;
    #pragma unroll
    for (int j = 0; j < 64; ++j) ms += msepart[t + 1024 * j];

    float p = (float)counts[t] * (1.0f / 65536.0f);
    float h = -p * log2f(p + 1e-10f);
    float u = (p > 0.f) ? 1.f : 0.f;
    #pragma unroll
    for (int off = 32; off > 0; off >>= 1) {
        h  += __shfl_down(h,  off, 64);
        u  += __shfl_down(u,  off, 64);
        ms += __shfl_down(ms, off, 64);
    }
    __shared__ float hs[16], us[16], mss[16];
    int lane = t & 63, w = t >> 6;
    if (lane == 0) { hs[w] = h; us[w] = u; mss[w] = ms; }
    __syncthreads();
    if (t == 0) {
        float H = 0.f, U = 0.f, M = 0.f;
        #pragma unroll
        for (int i = 0; i < 16; ++i) { H += hs[i]; U += us[i]; M += mss[i]; }
        float m = M * (1.0f / 16777216.0f);
        float loss = BETA * m + m;
        float perp = expf(H * 0.69314718055994530942f);
        outs[0] = loss;
        outs[1] = perp;
        outs[2] = U * (1.0f / 1024.0f);
        outs[3] = H;
    }
}

extern "C" void kernel_launch(void* const* d_in, const int* in_sizes, int n_in,
                              void* d_out, int out_size, void* d_ws, size_t ws_size,
                              hipStream_t stream) {
    const float* x  = (const float*)d_in[0];   // [65536, 256]
    const float* cb = (const float*)d_in[1];   // [1024, 256]
    float* out      = (float*)d_out;

    float* y        = out;                      // 16,777,216
    float* out_idxf = out + 16777216;           // 65,536
    float* outs     = out + 16777216 + 65536;   // loss, perp, usage, H

    // ws layout (bytes):
    // [0       .. 262143]  x2f (65536 f32)
    // [262144  .. 266239]  e2f (1024 f32)
    // [266240  .. 270335]  counts (1024 u32)
    // [270336  .. 270399]  (unused, align)
    // [270400  .. 1318975] rowlist (65536 rows x 8 ushort)
    // [1318976 .. 1843263] cs (1024 x 256 ushort, bf16 hi)
    // [1843264 .. 2105407] msepart (65536 f32)
    float*        x2f     = (float*)d_ws;
    float*        e2f     = (float*)((char*)d_ws + 262144);
    unsigned int* counts  = (unsigned int*)((char*)d_ws + 266240);
    ushort*       rowlist = (ushort*)((char*)d_ws + 270400);
    ushort*       cs      = (ushort*)((char*)d_ws + 1318976);
    float*        msepart = (float*)((char*)d_ws + 1843264);

    hipMemsetAsync((char*)d_ws + 266240, 0, 4096, stream);  // counts
    split_cb_kernel<<<KCODES / 4, 256, 0, stream>>>(cb, cs, e2f);
    screen_kernel<<<NROWS / 256, 256, 0, stream>>>(x, cs, e2f, x2f, rowlist);
    rescore_kernel<<<NROWS / 4, 256, 0, stream>>>(x, cb, x2f, e2f, rowlist,
                                                  out_idxf, counts, y, msepart);
    stats_kernel<<<1, 1024, 0, stream>>>(counts, msepart, outs);
}

// Round 6
// 198.405 us; speedup vs baseline: 1.1163x; 1.1163x over previous
//
#include <hip/hip_runtime.h>
#include <math.h>

#define D       256
#define KCODES  1024
#define NROWS   65536
#define BETA    0.25f
#define MARGIN  1e-3f
#define MAXSURV 7

typedef __attribute__((ext_vector_type(8))) short bf16x8;
typedef __attribute__((ext_vector_type(4))) float f32x4;

__device__ __forceinline__ unsigned int bf16_rne(float f) {
    unsigned int u = __float_as_uint(f);
    return (u + 0x7FFFu + ((u >> 16) & 1u)) >> 16;   // RNE bf16 (inputs are finite/normal)
}
__device__ __forceinline__ f32x4 mfma16(bf16x8 a, bf16x8 b, f32x4 c) {
    return __builtin_amdgcn_mfma_f32_16x16x32_bf16(a, b, c, 0, 0, 0);
}

// ---------- codebook -> bf16 (hi only, RNE): cs[k][0:256]; e2f exact ----------
__global__ __launch_bounds__(256) void split_cb_kernel(const float* __restrict__ cb,
                                                       ushort* __restrict__ cs,
                                                       float* __restrict__ e2f) {
    int code = blockIdx.x * 4 + (threadIdx.x >> 6);
    int lane = threadIdx.x & 63;
    float4 v = ((const float4*)(cb + (size_t)code * D))[lane];
    double s = (double)v.x * v.x + (double)v.y * v.y +
               (double)v.z * v.z + (double)v.w * v.w;
    ushort* ph = cs + (size_t)code * 256 + lane * 4;
    ph[0] = (ushort)bf16_rne(v.x); ph[1] = (ushort)bf16_rne(v.y);
    ph[2] = (ushort)bf16_rne(v.z); ph[3] = (ushort)bf16_rne(v.w);
    #pragma unroll
    for (int off = 32; off > 0; off >>= 1) s += __shfl_down(s, off, 64);
    if (lane == 0) e2f[code] = (float)s;
}

// ---------- MFMA screening v7: TLP build-out. 16 rows/wave (1 M-tile, af = 32 VGPR),
// 512-thread blocks (8 waves, 128 rows), grid 512 -> 2 blocks/CU = 16 waves/CU =
// 4 waves/SIMD (launch_bounds(512,4) caps VGPR at 128). Evidence (v4/v5/v6 triplet):
// kernel is latency-bound; waves/SIMD is the controlling variable, not pipe traffic.
// Per-row math, visit order, packed top-2 and merge identical to v6 -> rowlist
// bit-identical. ----------
__global__ __launch_bounds__(512, 4) void screen_kernel(
    const float* __restrict__ x, const ushort* __restrict__ cs,
    const float* __restrict__ e2f, float* __restrict__ x2f,
    ushort* __restrict__ rowlist)
{
    __shared__ __attribute__((aligned(16))) ushort Bt[2][32 * 264];  // 2 x 16,896 B
    // merge scratch aliased into Bt[0] (128 rows x 33 u32 = 16,896 B = sizeof(Bt[0])).
    // Safe: after the kt=31 barrier no wave reads/writes Bt[0] again (compute(31) reads
    // Bt[1] only); merge writes happen post-loop, reads after a further barrier.
    unsigned* mrg = (unsigned*)&Bt[0][0];
    #define MRG(r, j) mrg[(r) * 33 + (j)]

    const int tid  = threadIdx.x;
    const int wave = tid >> 6, lane = tid & 63;
    const int quad = lane >> 4, m = lane & 15;
    const int rowBase = blockIdx.x * 128;
    const int wrb = rowBase + wave * 16;       // this wave's 16 rows (1 M-tile)

    // ---- issue tile-0 staging loads first: latency hides under the A-fragment build ----
    const int sc = tid & 31, sp = tid >> 5;    // staging: code 0..31, part 0..15 (16 ushorts)
    bf16x8 stg[2];
    {
        const ushort* src = cs + (size_t)sc * 256 + sp * 16;
        stg[0] = *(const bf16x8*)&src[0];
        stg[1] = *(const bf16x8*)&src[8];
    }

    // ---- build A fragment (bf16 hi) in registers from fp32 x; accumulate exact x2 ----
    bf16x8 af[8];                              // 32 VGPRs
    {
        const float* xr = x + (size_t)(wrb + m) * D;
        double s = 0.0;
        #pragma unroll
        for (int c = 0; c < 8; ++c) {
            float4 f0 = *(const float4*)&xr[c * 32 + quad * 8];
            float4 f1 = *(const float4*)&xr[c * 32 + quad * 8 + 4];
            s += (double)f0.x * f0.x + (double)f0.y * f0.y +
                 (double)f0.z * f0.z + (double)f0.w * f0.w;
            s += (double)f1.x * f1.x + (double)f1.y * f1.y +
                 (double)f1.z * f1.z + (double)f1.w * f1.w;
            float ff[8] = {f0.x, f0.y, f0.z, f0.w, f1.x, f1.y, f1.z, f1.w};
            #pragma unroll
            for (int j = 0; j < 8; ++j) af[c][j] = (short)bf16_rne(ff[j]);
        }
        s += __shfl_xor(s, 16, 64);
        s += __shfl_xor(s, 32, 64);
        if (quad == 0) x2f[wrb + m] = (float)s;
    }

    // ---- packed top-2 per row-reg over this lane's code class ----
    unsigned u1[4], u2[4];
    #pragma unroll
    for (int r = 0; r < 4; ++r) { u1[r] = 0xFFFFFFFFu; u2[r] = 0xFFFFFFFFu; }

    // Pipeline per kt:  [ds_write stg(kt) -> buf[kt&1]]  barrier
    //                   [issue global loads stg := tile kt+1]  [compute(kt) from buf[kt&1]]
    for (int kt = 0; kt < KCODES / 32; ++kt) {
        {
            ushort* dst = &Bt[kt & 1][sc * 264 + sp * 16];
            *(bf16x8*)&dst[0] = stg[0];
            *(bf16x8*)&dst[8] = stg[1];
        }
        __syncthreads();                        // buf[kt&1] visible to all waves
        if (kt < KCODES / 32 - 1) {
            const ushort* src = cs + (size_t)((kt + 1) * 32 + sc) * 256 + sp * 16;
            stg[0] = *(const bf16x8*)&src[0];
            stg[1] = *(const bf16x8*)&src[8];
        }

        // e2 prefetch (+0.5 pack bias folded in) before the MFMA clusters
        float e2pa = e2f[kt * 32 + m] + 0.5f;
        float e2pb = e2f[kt * 32 + 16 + m] + 0.5f;

        const ushort* Bcur = &Bt[kt & 1][0];
        #pragma unroll
        for (int nt = 0; nt < 2; ++nt) {
            f32x4 acc = {0.f, 0.f, 0.f, 0.f};
            const ushort* bp = Bcur + (nt * 16 + m) * 264 + quad * 8;
            __builtin_amdgcn_s_setprio(1);
            #pragma unroll
            for (int c = 0; c < 8; ++c) {
                bf16x8 bh = *(const bf16x8*)&bp[c * 32];
                acc = mfma16(af[c], bh, acc);
            }
            __builtin_amdgcn_s_setprio(0);
            unsigned kcode = kt * 32 + nt * 16 + m;
            float e2p = nt ? e2pb : e2pa;
            #pragma unroll
            for (int r = 0; r < 4; ++r) {
                float d = fmaf(-2.f, acc[r], e2p);              // dist + 0.5 (> 0)
                unsigned u = (__float_as_uint(d) & 0xFFFFFC00u) | kcode;
                bool lt1 = u < u1[r];
                bool lt2 = u < u2[r];
                u2[r] = lt2 ? (lt1 ? u1[r] : u) : u2[r];
                u1[r] = lt1 ? u : u1[r];
            }
        }
    }

    // ---- per-row merge: 8 waves x 16 rows = 128 rows, single phase ----
    #pragma unroll
    for (int r = 0; r < 4; ++r) {
        int rowloc = wave * 16 + quad * 4 + r;
        MRG(rowloc, m * 2 + 0) = u1[r];
        MRG(rowloc, m * 2 + 1) = u2[r];
    }
    __syncthreads();
    if (tid < 128) {
        unsigned umin = 0xFFFFFFFFu;
        #pragma unroll
        for (int j = 0; j < 32; ++j) umin = min(umin, MRG(tid, j));
        float dfloor = __uint_as_float(umin & 0xFFFFFC00u);
        unsigned limu = (__float_as_uint(dfloor + MARGIN) & 0xFFFFFC00u) | 1023u;
        ushort out[8] = {0, 0, 0, 0, 0, 0, 0, 0};
        int cnt = 0;
        for (int j = 0; j < 32; ++j) {
            unsigned u = MRG(tid, j);
            if (u <= limu && cnt < MAXSURV) { out[1 + cnt] = (ushort)(u & 1023u); ++cnt; }
        }
        out[0] = (ushort)cnt;
        *(bf16x8*)&rowlist[(size_t)(rowBase + tid) * 8] = *(bf16x8*)out;
    }
    #undef MRG
}

// ---------- exact rescore + gather + mse partial: one wave per row ----------
__global__ __launch_bounds__(256) void rescore_kernel(
    const float* __restrict__ x, const float* __restrict__ cb,
    const float* __restrict__ x2f, const float* __restrict__ e2f,
    const ushort* __restrict__ rowlist, float* __restrict__ out_idxf,
    unsigned int* __restrict__ counts, float* __restrict__ y,
    float* __restrict__ msepart)
{
    int row  = blockIdx.x * 4 + (threadIdx.x >> 6);
    int lane = threadIdx.x & 63;
    const ushort* lst = rowlist + (size_t)row * 8;
    int cnt = lst[0];
    float4 xv = ((const float4*)(x + (size_t)row * D))[lane];

    int bk;
    if (cnt == 1) {
        bk = lst[1];                            // fast path: single survivor
    } else {
        float x2 = x2f[row];
        float bestd = 1e30f;
        int   bestk = 0;
        for (int s = 0; s < cnt; ++s) {
            int k = lst[1 + s];
            float4 cv = ((const float4*)(cb + (size_t)k * D))[lane];
            double p = (double)xv.x * cv.x + (double)xv.y * cv.y +
                       (double)xv.z * cv.z + (double)xv.w * cv.w;
            #pragma unroll
            for (int off = 32; off > 0; off >>= 1) p += __shfl_down(p, off, 64);
            float simf = (float)p;              // correctly-rounded f32 sim (lane 0 exact)
            float tt   = x2 + e2f[k];           // fl32(x2+e2)
            float dq   = tt - 2.0f * simf;      // reference comparator
            if (dq < bestd || (dq == bestd && k < bestk)) { bestd = dq; bestk = k; }
        }
        bk = __shfl(bestk, 0, 64);              // lane 0 had the exact sums
    }
    if (lane == 0) {
        out_idxf[row] = (float)bk;
        atomicAdd(&counts[bk], 1u);             // 1024 distinct addresses -> low contention
    }
    // gather + y + mse partial
    float4 q = ((const float4*)(cb + (size_t)bk * D))[lane];
    float4 dv;
    dv.x = q.x - xv.x; dv.y = q.y - xv.y; dv.z = q.z - xv.z; dv.w = q.w - xv.w;
    float4 yv;
    yv.x = xv.x + dv.x; yv.y = xv.y + dv.y; yv.z = xv.z + dv.z; yv.w = xv.w + dv.w;
    ((float4*)(y + (size_t)row * D))[lane] = yv;
    float s = dv.x * dv.x + dv.y * dv.y + dv.z * dv.z + dv.w * dv.w;
    #pragma unroll
    for (int off = 32; off > 0; off >>= 1) s += __shfl_down(s, off, 64);
    if (lane == 0) msepart[row] = s;            // plain store, no atomic
}

// ---------- final scalars: reduce msepart + counts -> loss, perplexity, usage, H ----------
__global__ __launch_bounds__(1024) void stats_kernel(
    const unsigned int* __restrict__ counts, const float* __restrict__ msepart,
    float* __restrict__ outs)
{
    int t = threadIdx.x;
    // mse partial reduction: 64 coalesced strided reads per thread
    float ms = 0.f;
    #pragma unroll
    for (int j = 0; j < 64; ++j) ms += msepart[t + 1024 * j];

    float p = (float)counts[t] * (1.0f / 65536.0f);
    float h = -p * log2f(p + 1e-10f);
    float u = (p > 0.f) ? 1.f : 0.f;
    #pragma unroll
    for (int off = 32; off > 0; off >>= 1) {
        h  += __shfl_down(h,  off, 64);
        u  += __shfl_down(u,  off, 64);
        ms += __shfl_down(ms, off, 64);
    }
    __shared__ float hs[16], us[16], mss[16];
    int lane = t & 63, w = t >> 6;
    if (lane == 0) { hs[w] = h; us[w] = u; mss[w] = ms; }
    __syncthreads();
    if (t == 0) {
        float H = 0.f, U = 0.f, M = 0.f;
        #pragma unroll
        for (int i = 0; i < 16; ++i) { H += hs[i]; U += us[i]; M += mss[i]; }
        float m = M * (1.0f / 16777216.0f);
        float loss = BETA * m + m;
        float perp = expf(H * 0.69314718055994530942f);
        outs[0] = loss;
        outs[1] = perp;
        outs[2] = U * (1.0f / 1024.0f);
        outs[3] = H;
    }
}

extern "C" void kernel_launch(void* const* d_in, const int* in_sizes, int n_in,
                              void* d_out, int out_size, void* d_ws, size_t ws_size,
                              hipStream_t stream) {
    const float* x  = (const float*)d_in[0];   // [65536, 256]
    const float* cb = (const float*)d_in[1];   // [1024, 256]
    float* out      = (float*)d_out;

    float* y        = out;                      // 16,777,216
    float* out_idxf = out + 16777216;           // 65,536
    float* outs     = out + 16777216 + 65536;   // loss, perp, usage, H

    // ws layout (bytes):
    // [0       .. 262143]  x2f (65536 f32)
    // [262144  .. 266239]  e2f (1024 f32)
    // [266240  .. 270335]  counts (1024 u32)
    // [270336  .. 270399]  (unused, align)
    // [270400  .. 1318975] rowlist (65536 rows x 8 ushort)
    // [1318976 .. 1843263] cs (1024 x 256 ushort, bf16 hi)
    // [1843264 .. 2105407] msepart (65536 f32)
    float*        x2f     = (float*)d_ws;
    float*        e2f     = (float*)((char*)d_ws + 262144);
    unsigned int* counts  = (unsigned int*)((char*)d_ws + 266240);
    ushort*       rowlist = (ushort*)((char*)d_ws + 270400);
    ushort*       cs      = (ushort*)((char*)d_ws + 1318976);
    float*        msepart = (float*)((char*)d_ws + 1843264);

    hipMemsetAsync((char*)d_ws + 266240, 0, 4096, stream);  // counts
    split_cb_kernel<<<KCODES / 4, 256, 0, stream>>>(cb, cs, e2f);
    screen_kernel<<<NROWS / 128, 512, 0, stream>>>(x, cs, e2f, x2f, rowlist);
    rescore_kernel<<<NROWS / 4, 256, 0, stream>>>(x, cb, x2f, e2f, rowlist,
                                                  out_idxf, counts, y, msepart);
    stats_kernel<<<1, 1024, 0, stream>>>(counts, msepart, outs);
}

// Round 7
// 191.853 us; speedup vs baseline: 1.1544x; 1.0342x over previous
//
#include <hip/hip_runtime.h>
#include <math.h>

#define D       256
#define KCODES  1024
#define NROWS   65536
#define BETA    0.25f
#define MARGIN  1e-3f
#define MAXSURV 7

typedef __attribute__((ext_vector_type(8))) short bf16x8;
typedef __attribute__((ext_vector_type(4))) float f32x4;

__device__ __forceinline__ unsigned int bf16_rne(float f) {
    unsigned int u = __float_as_uint(f);
    return (u + 0x7FFFu + ((u >> 16) & 1u)) >> 16;   // RNE bf16 (inputs are finite/normal)
}
__device__ __forceinline__ f32x4 mfma16(bf16x8 a, bf16x8 b, f32x4 c) {
    return __builtin_amdgcn_mfma_f32_16x16x32_bf16(a, b, c, 0, 0, 0);
}

// ---------- codebook -> bf16 (hi only, RNE): cs[k][0:256]; e2f exact ----------
__global__ __launch_bounds__(256) void split_cb_kernel(const float* __restrict__ cb,
                                                       ushort* __restrict__ cs,
                                                       float* __restrict__ e2f) {
    int code = blockIdx.x * 4 + (threadIdx.x >> 6);
    int lane = threadIdx.x & 63;
    float4 v = ((const float4*)(cb + (size_t)code * D))[lane];
    double s = (double)v.x * v.x + (double)v.y * v.y +
               (double)v.z * v.z + (double)v.w * v.w;
    ushort* ph = cs + (size_t)code * 256 + lane * 4;
    ph[0] = (ushort)bf16_rne(v.x); ph[1] = (ushort)bf16_rne(v.y);
    ph[2] = (ushort)bf16_rne(v.z); ph[3] = (ushort)bf16_rne(v.w);
    #pragma unroll
    for (int off = 32; off > 0; off >>= 1) s += __shfl_down(s, off, 64);
    if (lane == 0) e2f[code] = (float)s;
}

// ---------- v8: screen + rescore FUSED. Screen part identical to v7 (16 rows/wave,
// 512-thread blocks, 4 waves/SIMD). After the merge, survivors stay in LDS and each
// wave finishes its own 16 rows in-block: exact f64 rescore for cnt>1 rows (math
// verbatim from the old rescore_kernel -> bit-identical), cb gather, y = x + (q - x),
// mse reduce -> msepart. Deletes the serial rescore kernel; its memory phase overlaps
// other blocks' compute phase. ----------
__global__ __launch_bounds__(512, 4) void screen_kernel(
    const float* __restrict__ x, const ushort* __restrict__ cs,
    const float* __restrict__ e2f, const float* __restrict__ cb,
    float* __restrict__ out_idxf, unsigned int* __restrict__ counts,
    float* __restrict__ y, float* __restrict__ msepart)
{
    __shared__ __attribute__((aligned(16))) ushort Bt[2][32 * 264];  // 2 x 16,896 B
    __shared__ float x2s[128];                 // per-local-row exact |x|^2
    // merge scratch aliased into Bt[0] (128 rows x 33 u32 = 16,896 B = sizeof(Bt[0])).
    // Safe: after the kt=31 barrier no wave touches Bt[0] (compute(31) reads Bt[1]).
    // Survivor lists are parked in the first 16 B of each merge row (same-thread reuse).
    unsigned* mrg = (unsigned*)&Bt[0][0];
    #define MRG(r, j) mrg[(r) * 33 + (j)]

    const int tid  = threadIdx.x;
    const int wave = tid >> 6, lane = tid & 63;
    const int quad = lane >> 4, m = lane & 15;
    const int rowBase = blockIdx.x * 128;
    const int wrb = rowBase + wave * 16;       // this wave's 16 rows (1 M-tile)

    // ---- issue tile-0 staging loads first: latency hides under the A-fragment build ----
    const int sc = tid & 31, sp = tid >> 5;    // staging: code 0..31, part 0..15 (16 ushorts)
    bf16x8 stg[2];
    {
        const ushort* src = cs + (size_t)sc * 256 + sp * 16;
        stg[0] = *(const bf16x8*)&src[0];
        stg[1] = *(const bf16x8*)&src[8];
    }

    // ---- build A fragment (bf16 hi) in registers from fp32 x; accumulate exact x2 ----
    bf16x8 af[8];                              // 32 VGPRs
    {
        const float* xr = x + (size_t)(wrb + m) * D;
        double s = 0.0;
        #pragma unroll
        for (int c = 0; c < 8; ++c) {
            float4 f0 = *(const float4*)&xr[c * 32 + quad * 8];
            float4 f1 = *(const float4*)&xr[c * 32 + quad * 8 + 4];
            s += (double)f0.x * f0.x + (double)f0.y * f0.y +
                 (double)f0.z * f0.z + (double)f0.w * f0.w;
            s += (double)f1.x * f1.x + (double)f1.y * f1.y +
                 (double)f1.z * f1.z + (double)f1.w * f1.w;
            float ff[8] = {f0.x, f0.y, f0.z, f0.w, f1.x, f1.y, f1.z, f1.w};
            #pragma unroll
            for (int j = 0; j < 8; ++j) af[c][j] = (short)bf16_rne(ff[j]);
        }
        s += __shfl_xor(s, 16, 64);
        s += __shfl_xor(s, 32, 64);
        if (quad == 0) x2s[wave * 16 + m] = (float)s;
    }

    // ---- packed top-2 per row-reg over this lane's code class ----
    unsigned u1[4], u2[4];
    #pragma unroll
    for (int r = 0; r < 4; ++r) { u1[r] = 0xFFFFFFFFu; u2[r] = 0xFFFFFFFFu; }

    // Pipeline per kt:  [ds_write stg(kt) -> buf[kt&1]]  barrier
    //                   [issue global loads stg := tile kt+1]  [compute(kt) from buf[kt&1]]
    for (int kt = 0; kt < KCODES / 32; ++kt) {
        {
            ushort* dst = &Bt[kt & 1][sc * 264 + sp * 16];
            *(bf16x8*)&dst[0] = stg[0];
            *(bf16x8*)&dst[8] = stg[1];
        }
        __syncthreads();                        // buf[kt&1] visible to all waves
        if (kt < KCODES / 32 - 1) {
            const ushort* src = cs + (size_t)((kt + 1) * 32 + sc) * 256 + sp * 16;
            stg[0] = *(const bf16x8*)&src[0];
            stg[1] = *(const bf16x8*)&src[8];
        }

        // e2 prefetch (+0.5 pack bias folded in) before the MFMA clusters
        float e2pa = e2f[kt * 32 + m] + 0.5f;
        float e2pb = e2f[kt * 32 + 16 + m] + 0.5f;

        const ushort* Bcur = &Bt[kt & 1][0];
        #pragma unroll
        for (int nt = 0; nt < 2; ++nt) {
            f32x4 acc = {0.f, 0.f, 0.f, 0.f};
            const ushort* bp = Bcur + (nt * 16 + m) * 264 + quad * 8;
            __builtin_amdgcn_s_setprio(1);
            #pragma unroll
            for (int c = 0; c < 8; ++c) {
                bf16x8 bh = *(const bf16x8*)&bp[c * 32];
                acc = mfma16(af[c], bh, acc);
            }
            __builtin_amdgcn_s_setprio(0);
            unsigned kcode = kt * 32 + nt * 16 + m;
            float e2p = nt ? e2pb : e2pa;
            #pragma unroll
            for (int r = 0; r < 4; ++r) {
                float d = fmaf(-2.f, acc[r], e2p);              // dist + 0.5 (> 0)
                unsigned u = (__float_as_uint(d) & 0xFFFFFC00u) | kcode;
                bool lt1 = u < u1[r];
                bool lt2 = u < u2[r];
                u2[r] = lt2 ? (lt1 ? u1[r] : u) : u2[r];
                u1[r] = lt1 ? u : u1[r];
            }
        }
    }

    // ---- per-row merge: 8 waves x 16 rows = 128 rows, single phase ----
    #pragma unroll
    for (int r = 0; r < 4; ++r) {
        int rowloc = wave * 16 + quad * 4 + r;
        MRG(rowloc, m * 2 + 0) = u1[r];
        MRG(rowloc, m * 2 + 1) = u2[r];
    }
    __syncthreads();
    if (tid < 128) {
        unsigned umin = 0xFFFFFFFFu;
        #pragma unroll
        for (int j = 0; j < 32; ++j) umin = min(umin, MRG(tid, j));
        float dfloor = __uint_as_float(umin & 0xFFFFFC00u);
        unsigned limu = (__float_as_uint(dfloor + MARGIN) & 0xFFFFFC00u) | 1023u;
        ushort out[8] = {0, 0, 0, 0, 0, 0, 0, 0};
        int cnt = 0;
        for (int j = 0; j < 32; ++j) {
            unsigned u = MRG(tid, j);
            if (u <= limu && cnt < MAXSURV) { out[1 + cnt] = (ushort)(u & 1023u); ++cnt; }
        }
        out[0] = (ushort)cnt;
        // park survivors in the first 16 B of this thread's own merge row (reads done)
        *(bf16x8*)&mrg[tid * 33] = *(bf16x8*)out;
    }
    __syncthreads();                            // survivor lists visible to all waves

    // ---- fused rescore/gather tail: each wave finishes its own 16 rows ----
    #pragma unroll 2
    for (int i = 0; i < 16; ++i) {
        int rl  = wave * 16 + i;
        int row = rowBase + rl;
        const ushort* lst = (const ushort*)&mrg[rl * 33];
        int cnt = lst[0];
        float4 xv = ((const float4*)(x + (size_t)row * D))[lane];

        int bk;
        if (cnt == 1) {
            bk = lst[1];                        // fast path: single survivor
        } else {
            float x2 = x2s[rl];
            float bestd = 1e30f;
            int   bestk = 0;
            for (int s = 0; s < cnt; ++s) {
                int k = lst[1 + s];
                float4 cv = ((const float4*)(cb + (size_t)k * D))[lane];
                double p = (double)xv.x * cv.x + (double)xv.y * cv.y +
                           (double)xv.z * cv.z + (double)xv.w * cv.w;
                #pragma unroll
                for (int off = 32; off > 0; off >>= 1) p += __shfl_down(p, off, 64);
                float simf = (float)p;          // correctly-rounded f32 sim (lane 0 exact)
                float tt   = x2 + e2f[k];       // fl32(x2+e2)
                float dq   = tt - 2.0f * simf;  // reference comparator
                if (dq < bestd || (dq == bestd && k < bestk)) { bestd = dq; bestk = k; }
            }
            bk = __shfl(bestk, 0, 64);          // lane 0 had the exact sums
        }
        if (lane == 0) {
            out_idxf[row] = (float)bk;
            atomicAdd(&counts[bk], 1u);         // 1024 distinct addresses -> low contention
        }
        // gather + y + mse partial (identical op order to old rescore_kernel)
        float4 q = ((const float4*)(cb + (size_t)bk * D))[lane];
        float4 dv;
        dv.x = q.x - xv.x; dv.y = q.y - xv.y; dv.z = q.z - xv.z; dv.w = q.w - xv.w;
        float4 yv;
        yv.x = xv.x + dv.x; yv.y = xv.y + dv.y; yv.z = xv.z + dv.z; yv.w = xv.w + dv.w;
        ((float4*)(y + (size_t)row * D))[lane] = yv;
        float s = dv.x * dv.x + dv.y * dv.y + dv.z * dv.z + dv.w * dv.w;
        #pragma unroll
        for (int off = 32; off > 0; off >>= 1) s += __shfl_down(s, off, 64);
        if (lane == 0) msepart[row] = s;        // plain store, no atomic
    }
    #undef MRG
}

// ---------- final scalars: reduce msepart + counts -> loss, perplexity, usage, H ----------
__global__ __launch_bounds__(1024) void stats_kernel(
    const unsigned int* __restrict__ counts, const float* __restrict__ msepart,
    float* __restrict__ outs)
{
    int t = threadIdx.x;
    // mse partial reduction: 64 coalesced strided reads per thread
    float ms = 0.f;
    #pragma unroll
    for (int j = 0; j < 64; ++j) ms += msepart[t + 1024 * j];

    float p = (float)counts[t] * (1.0f / 65536.0f);
    float h = -p * log2f(p + 1e-10f);
    float u = (p > 0.f) ? 1.f : 0.f;
    #pragma unroll
    for (int off = 32; off > 0; off >>= 1) {
        h  += __shfl_down(h,  off, 64);
        u  += __shfl_down(u,  off, 64);
        ms += __shfl_down(ms, off, 64);
    }
    __shared__ float hs[16], us[16], mss[16];
    int lane = t & 63, w = t >> 6;
    if (lane == 0) { hs[w] = h; us[w] = u; mss[w] = ms; }
    __syncthreads();
    if (t == 0) {
        float H = 0.f, U = 0.f, M = 0.f;
        #pragma unroll
        for (int i = 0; i < 16; ++i) { H += hs[i]; U += us[i]; M += mss[i]; }
        float m = M * (1.0f / 16777216.0f);
        float loss = BETA * m + m;
        float perp = expf(H * 0.69314718055994530942f);
        outs[0] = loss;
        outs[1] = perp;
        outs[2] = U * (1.0f / 1024.0f);
        outs[3] = H;
    }
}

extern "C" void kernel_launch(void* const* d_in, const int* in_sizes, int n_in,
                              void* d_out, int out_size, void* d_ws, size_t ws_size,
                              hipStream_t stream) {
    const float* x  = (const float*)d_in[0];   // [65536, 256]
    const float* cb = (const float*)d_in[1];   // [1024, 256]
    float* out      = (float*)d_out;

    float* y        = out;                      // 16,777,216
    float* out_idxf = out + 16777216;           // 65,536
    float* outs     = out + 16777216 + 65536;   // loss, perp, usage, H

    // ws layout (bytes):
    // [0       .. 262143]  (unused; was x2f)
    // [262144  .. 266239]  e2f (1024 f32)
    // [266240  .. 270335]  counts (1024 u32)
    // [270336  .. 270399]  (unused, align)
    // [270400  .. 1318975] (unused; was rowlist)
    // [1318976 .. 1843263] cs (1024 x 256 ushort, bf16 hi)
    // [1843264 .. 2105407] msepart (65536 f32)
    float*        e2f     = (float*)((char*)d_ws + 262144);
    unsigned int* counts  = (unsigned int*)((char*)d_ws + 266240);
    ushort*       cs      = (ushort*)((char*)d_ws + 1318976);
    float*        msepart = (float*)((char*)d_ws + 1843264);

    hipMemsetAsync((char*)d_ws + 266240, 0, 4096, stream);  // counts
    split_cb_kernel<<<KCODES / 4, 256, 0, stream>>>(cb, cs, e2f);
    screen_kernel<<<NROWS / 128, 512, 0, stream>>>(x, cs, e2f, cb,
                                                   out_idxf, counts, y, msepart);
    stats_kernel<<<1, 1024, 0, stream>>>(counts, msepart, outs);
}